// Round 8
// baseline (269.814 us; speedup 1.0000x reference)
//
#include <hip/hip_runtime.h>
#include <math.h>

#define SE_B     32
#define SE_C     256
#define SE_R     16
#define SE_HW    16384                 // floats per plane (128*128)
#define SE_NP    (SE_B * SE_C)         // 8192 planes
#define CHUNK_B  8                     // batches per chunk (8*16MB = 128MB << 256MB L3)
#define CHUNK_P  (CHUNK_B * SE_C)      // 2048 planes per chunk
#define NCHUNK   (SE_B / CHUNK_B)      // 4 chunks

typedef float v4f __attribute__((ext_vector_type(4)));

// ---- K1: pool one chunk. One block per plane; PLAIN loads so x allocates
// in L3 (the next kernel re-reads it from there). ----
__global__ __launch_bounds__(256) void se_pool_chunk(const float* __restrict__ x,
                                                     float* __restrict__ pooled,
                                                     int base_plane) {
    const int plane = base_plane + blockIdx.x;
    const int t = threadIdx.x;
    const v4f* xv = reinterpret_cast<const v4f*>(x) + (size_t)plane * (SE_HW / 4);
    float s = 0.f;
#pragma unroll
    for (int k = 0; k < 16; ++k) {
        v4f v = xv[k * 256 + t];
        s += (v.x + v.y) + (v.z + v.w);
    }
#pragma unroll
    for (int off = 32; off > 0; off >>= 1) s += __shfl_down(s, off, 64);
    __shared__ float ws[4];
    if ((t & 63) == 0) ws[t >> 6] = s;
    __syncthreads();
    if (t == 0) pooled[plane] = ((ws[0] + ws[1]) + (ws[2] + ws[3])) * (1.0f / SE_HW);
}

// ---- K2: fused gate + scale for one chunk. One block per plane.
// Each block redundantly computes its own gate value (tiny MLP on the
// 256-float pooled row), then scales its plane: x read comes from L3
// (just written by K1 of the same chunk), out goes NT to HBM. ----
__global__ __launch_bounds__(256) void se_scale_chunk(const float* __restrict__ x,
                                                      const float* __restrict__ pooled,
                                                      const float* __restrict__ w1,   // [R,C]
                                                      const float* __restrict__ w2,   // [C,R]
                                                      float* __restrict__ out,
                                                      int base_plane) {
    const int plane = base_plane + blockIdx.x;
    const int b = plane >> 8;                 // plane / 256
    const int c = plane & 255;                // plane % 256
    const int t = threadIdx.x;

    __shared__ float p_lds[SE_C];
    __shared__ float hpart[SE_R][SE_R + 1];
    __shared__ float h_lds[SE_R];
    __shared__ float g_lds;

    // gate for (b,c), computed cooperatively by the block
    p_lds[t] = pooled[b * SE_C + t];
    __syncthreads();
    {   // h[r] = relu(sum_c p[c]*w1[r,c]) ; C split into 16 segments
        const int r = t & 15, seg = t >> 4;
        float acc = 0.f;
#pragma unroll
        for (int j = 0; j < 16; ++j) {
            const int cc = seg * 16 + j;
            acc = fmaf(p_lds[cc], w1[r * SE_C + cc], acc);
        }
        hpart[r][seg] = acc;
    }
    __syncthreads();
    if (t < SE_R) {
        float acc = 0.f;
#pragma unroll
        for (int j = 0; j < 16; ++j) acc += hpart[t][j];
        h_lds[t] = fmaxf(acc, 0.f);
    }
    __syncthreads();
    if (t == 0) {
        float acc = 0.f;
#pragma unroll
        for (int r = 0; r < SE_R; ++r) acc = fmaf(h_lds[r], w2[c * SE_R + r], acc);
        g_lds = 1.0f / (1.0f + expf(-acc));
    }
    __syncthreads();
    const float g = g_lds;

    // scale the plane: L3-hit reads, NT stores
    const v4f* xv = reinterpret_cast<const v4f*>(x) + (size_t)plane * (SE_HW / 4);
    v4f* ov = reinterpret_cast<v4f*>(out) + (size_t)plane * (SE_HW / 4);
#pragma unroll
    for (int k = 0; k < 16; ++k) {
        v4f v = xv[k * 256 + t];
        v *= g;
        __builtin_nontemporal_store(v, &ov[k * 256 + t]);
    }
}

extern "C" void kernel_launch(void* const* d_in, const int* in_sizes, int n_in,
                              void* d_out, int out_size, void* d_ws, size_t ws_size,
                              hipStream_t stream) {
    const float* x  = (const float*)d_in[0];   // [32,256,128,128]
    const float* w1 = (const float*)d_in[1];   // [16,256]
    const float* w2 = (const float*)d_in[2];   // [256,16]
    float* out = (float*)d_out;
    float* pooled = (float*)d_ws;              // 8192 floats = 32 KiB

    for (int ch = 0; ch < NCHUNK; ++ch) {
        const int base = ch * CHUNK_P;
        se_pool_chunk<<<CHUNK_P, 256, 0, stream>>>(x, pooled, base);
        se_scale_chunk<<<CHUNK_P, 256, 0, stream>>>(x, pooled, w1, w2, out, base);
    }
}